// Round 1
// baseline (176.406 us; speedup 1.0000x reference)
//
#include <hip/hip_runtime.h>

// JointBilateralFilter B=16,C=1,H=768,W=1024 fp32, 9x9, sigma_s=2, sigma_r=0.1.
// valid = (sparse != 1.0); constant pad 1.0 => out-of-image taps never contribute
// (reflect-pad of depth is dead code). ~5% valid density.
//
// R7: PIXEL-PACKED gather-scan. Each lane owns TWO pixels (gx, gx+8); wave tile
// 16 wide x 8 tall = 128 px (2x the px per wave => fixed overhead halves per px,
// which R4/R5 showed is ~75% of the cost). All per-entry float math is 2-wide
// ext_vector fp32 => v_pk_{add,mul,fma}_f32 (full-rate packed fp32 on gfx950).
// LDS spatial table T[dy+15][dx+23] = in-box? CS*(dy^2+dx^2) : -1e30 folds the
// box test; slot1 (pixel at gx+8) reads the same row at column-8 => the two
// reads are {tb[8], tb[0]} off one address (ds_read2-mergeable). Entry coords
// are SALU (tile constants readfirstlane'd). Table build: fill -1e30 + write
// only the 81 in-box cells. atomics/scatter abandoned (R6: LDS fp atomicAdd
// => CAS loop => 20x regression).
//
// R8 (this round): unchanged resubmit — prior bench attempt died to an infra
// failure (container failed twice); re-establish baseline counters before edit.

#define HH 768
#define WW 1024
#define BB 16
#define CS (-0.18033688011112042f)   /* -log2(e)/8  */
#define CR (-72.13475204444817f)     /* -50*log2(e) */

#define TS 48                        /* table row stride (floats): 2-way banks */
#define TROWS 31                     /* dy in [-15,15] */
#define TSIZE (TROWS * TS)           /* 1488 floats = 5952 B */

typedef float f2 __attribute__((ext_vector_type(2)));

__device__ __forceinline__ int rfl(int x) { return __builtin_amdgcn_readfirstlane(x); }
__device__ __forceinline__ float rlanef(float v, int b) {
    return __int_as_float(__builtin_amdgcn_readlane(__float_as_int(v), b));
}
__device__ __forceinline__ f2 splat(float x) { f2 r; r.x = x; r.y = x; return r; }

__global__ __launch_bounds__(256) void jbf_kernel(
    const float* __restrict__ sparse,
    const float* __restrict__ depth,
    float* __restrict__ out)
{
    __shared__ float Tab[TSIZE];
    const int tid  = (int)threadIdx.x;
    const int lane = tid & 63;
    const int wv   = tid >> 6;                    // 4 waves/block, 2x2 tiles

    // ---- table build: fill -1e30, barrier, write the 81 in-box cells ----
    for (int i = tid; i < TSIZE; i += 256) Tab[i] = -1e30f;
    __syncthreads();
    if (tid < 81) {
        const int rr = (tid * 57) >> 9;           // tid/9 for tid<81
        const int cc = tid - 9 * rr;
        const float dy = (float)(rr - 4), dx = (float)(cc - 4);
        Tab[(rr + 11) * TS + cc + 19] = CS * fmaf(dy, dy, dx * dx);
    }
    __syncthreads();

    // ---- wave-uniform tile constants (SGPRs) ----
    const int tx = rfl(((int)blockIdx.x << 5) + ((wv & 1) << 4));   // 16-wide tile
    const int ty = rfl(((int)blockIdx.y << 4) + ((wv >> 1) << 3));  // 8-tall tile
    const int px0 = rfl(min(max(tx - 4, 0), WW - 24));              // 24-col window
    const int py0 = rfl(min(max(ty - 4, 0), HH - 16));              // 16-row window
    const int txoff = tx - px0;                   // 0..8
    const int tyoff = ty - py0;                   // 0..8

    const size_t plane = (size_t)blockIdx.z * (size_t)(HH * WW);
    const float* sp = sparse + plane;
    const float* dp = depth  + plane;

    // ---- stage 16x24 window: 3 float2 per lane per input ----
    const int r  = lane >> 2;                     // 0..15 window row
    const int c0 = (lane & 3) << 1;               // float2 col 0,2,4,6 (+8 per j)
    const float* wbs = sp + (py0 + r) * WW + px0 + c0;
    const float* wbd = dp + (py0 + r) * WW + px0 + c0;
    const f2 s20 = *(const f2*)(wbs);
    const f2 s21 = *(const f2*)(wbs + 8);
    const f2 s22 = *(const f2*)(wbs + 16);
    const f2 d20 = *(const f2*)(wbd);
    const f2 d21 = *(const f2*)(wbd + 8);
    const f2 d22 = *(const f2*)(wbd + 16);

    // ---- per-lane pixel pair (gx, gx+8) ----
    const int my = lane >> 3, mx = lane & 7;
    const int gy = ty + my, gx = tx + mx;
    const float myd0 = dp[gy * WW + gx];
    const float myd1 = dp[gy * WW + gx + 8];
    f2 nmyd; nmyd.x = -myd0; nmyd.y = -myd1;
    const int clane_w = my * TS + mx;             // per-lane table float offset

    f2 numA = splat(0.0f), denA = splat(0.0f);
    f2 numB = splat(0.0f), denB = splat(0.0f);
    const f2 crp = splat(CR);

    // SALU base: 48*(dy+15) + (dx0+23) - 8 decomposition (lane part = clane_w)
    const int sbase0 = TS * (15 - tyoff) + (23 - txoff) - 8;

    #pragma unroll
    for (int j = 0; j < 3; ++j) {
        const f2 s2 = (j == 0) ? s20 : (j == 1) ? s21 : s22;
        const f2 d2 = (j == 0) ? d20 : (j == 1) ? d21 : d22;
        #pragma unroll
        for (int k = 0; k < 2; ++k) {
            const float svk = k ? s2.y : s2.x;
            const float dvk = k ? d2.y : d2.x;
            const int sbase = sbase0 + 8 * j + k;          // SALU
            unsigned long long m = __ballot(svk != 1.0f);
            while (m) {                                     // uniform scalar loop
                const int b0 = (int)__builtin_ctzll(m);
                m &= (m - 1ull);
                {
                    const float sv_e = rlanef(svk, b0);
                    const float dv_e = rlanef(dvk, b0);
                    const int SW = sbase + (b0 >> 2) * TS + ((b0 & 3) << 1); // SALU
                    const float* tb = Tab + (SW - clane_w); // one v_sub
                    f2 tp; tp.x = tb[8]; tp.y = tb[0];      // ds_read2_b32
                    const f2 diff = nmyd + splat(dv_e);
                    const f2 q = diff * crp;
                    const f2 arg = q * diff + tp;           // pk_fma
                    f2 w; w.x = __builtin_amdgcn_exp2f(arg.x);
                    w.y = __builtin_amdgcn_exp2f(arg.y);
                    denA += w;
                    numA += w * splat(sv_e);                // pk_fma
                }
                if (m) {                                    // independent B chain
                    const int b1 = (int)__builtin_ctzll(m);
                    m &= (m - 1ull);
                    const float sv_e = rlanef(svk, b1);
                    const float dv_e = rlanef(dvk, b1);
                    const int SW = sbase + (b1 >> 2) * TS + ((b1 & 3) << 1);
                    const float* tb = Tab + (SW - clane_w);
                    f2 tp; tp.x = tb[8]; tp.y = tb[0];
                    const f2 diff = nmyd + splat(dv_e);
                    const f2 q = diff * crp;
                    const f2 arg = q * diff + tp;
                    f2 w; w.x = __builtin_amdgcn_exp2f(arg.x);
                    w.y = __builtin_amdgcn_exp2f(arg.y);
                    denB += w;
                    numB += w * splat(sv_e);
                }
            }
        }
    }

    const float n0 = numA.x + numB.x, n1 = numA.y + numB.y;
    const float e0 = denA.x + denB.x, e1 = denA.y + denB.y;
    float r0 = n0 * __builtin_amdgcn_rcpf(e0 + 1e-8f);
    r0 = (e0 < 1e-8f) ? 1.0f : r0;
    float r1 = n1 * __builtin_amdgcn_rcpf(e1 + 1e-8f);
    r1 = (e1 < 1e-8f) ? 1.0f : r1;
    float* op = out + plane + (size_t)gy * WW + gx;
    op[0] = r0;
    op[8] = r1;
}

extern "C" void kernel_launch(void* const* d_in, const int* in_sizes, int n_in,
                              void* d_out, int out_size, void* d_ws, size_t ws_size,
                              hipStream_t stream)
{
    const float* sparse = (const float*)d_in[0];
    const float* depth  = (const float*)d_in[1];
    float* out = (float*)d_out;
    dim3 grid(WW / 32, HH / 16, BB);   // 32 x 48 x 16 blocks, 4 waves each
    jbf_kernel<<<grid, dim3(256, 1, 1), 0, stream>>>(sparse, depth, out);
}

// Round 2
// 174.521 us; speedup vs baseline: 1.0108x; 1.0108x over previous
//
#include <hip/hip_runtime.h>

// JointBilateralFilter B=16,C=1,H=768,W=1024 fp32, 9x9, sigma_s=2, sigma_r=0.1.
// valid = (sparse != 1.0); constant pad 1.0 => out-of-image taps never contribute
// (reflect-pad of depth is dead code). ~5% valid density.
//
// R7: PIXEL-PACKED gather-scan. Each lane owns TWO pixels (gx, gx+8); wave tile
// 16 wide x 8 tall = 128 px. All per-entry float math is 2-wide ext_vector fp32
// => v_pk_{add,mul,fma}_f32. LDS spatial table folds the box test via -1e30
// sentinel; slot1 reads the same row at column-8 => {tb[8], tb[0]} is one
// ds_read2_b32. Entry coords are SALU. atomics/scatter abandoned (R6: LDS fp
// atomicAdd => CAS loop => 20x regression).
//
// R9 (this round): BANK-CONFLICT FIX. rocprof R8: SQ_LDS_BANK_CONFLICT=7.59M
// over 1.89M ds_read2 = 4.0 extra cyc/read — exact 4-way-conflict signature of
// TS=48 (48 mod 32 = 16 => lanes (my,mx),(my+2,mx) share a bank). TS=68
// (== 4 mod 32): bank = (4*my+mx) mod 32 maps 64 lanes exactly 2-per-bank =>
// 2-way = free (m136). Also float4 sentinel fill (6 scalar iters -> 2-3
// ds_write_b128) to trim per-block fixed overhead.

#define HH 768
#define WW 1024
#define BB 16
#define CS (-0.18033688011112042f)   /* -log2(e)/8  */
#define CR (-72.13475204444817f)     /* -50*log2(e) */

#define TS 68                        /* table row stride: 68 mod 32 = 4 => 2-way banks (free) */
#define TROWS 31                     /* dy in [-15,15] */
#define TSIZE (TROWS * TS)           /* 2108 floats = 8432 B */
#define TF4   (TSIZE / 4)            /* 527 float4 — TSIZE is divisible by 4 */

typedef float f2 __attribute__((ext_vector_type(2)));

__device__ __forceinline__ int rfl(int x) { return __builtin_amdgcn_readfirstlane(x); }
__device__ __forceinline__ float rlanef(float v, int b) {
    return __int_as_float(__builtin_amdgcn_readlane(__float_as_int(v), b));
}
__device__ __forceinline__ f2 splat(float x) { f2 r; r.x = x; r.y = x; return r; }

__global__ __launch_bounds__(256) void jbf_kernel(
    const float* __restrict__ sparse,
    const float* __restrict__ depth,
    float* __restrict__ out)
{
    __shared__ __align__(16) float Tab[TSIZE];
    const int tid  = (int)threadIdx.x;
    const int lane = tid & 63;
    const int wv   = tid >> 6;                    // 4 waves/block, 2x2 tiles

    // ---- table build: float4 fill -1e30, barrier, write the 81 in-box cells ----
    {
        float4 s; s.x = -1e30f; s.y = -1e30f; s.z = -1e30f; s.w = -1e30f;
        float4* t4 = (float4*)Tab;
        #pragma unroll
        for (int i = 0; i < 3; ++i) {
            const int idx = tid + 256 * i;
            if (idx < TF4) t4[idx] = s;
        }
    }
    __syncthreads();
    if (tid < 81) {
        const int rr = (tid * 57) >> 9;           // tid/9 for tid<81
        const int cc = tid - 9 * rr;
        const float dy = (float)(rr - 4), dx = (float)(cc - 4);
        Tab[(rr + 11) * TS + cc + 19] = CS * fmaf(dy, dy, dx * dx);
    }
    __syncthreads();

    // ---- wave-uniform tile constants (SGPRs) ----
    const int tx = rfl(((int)blockIdx.x << 5) + ((wv & 1) << 4));   // 16-wide tile
    const int ty = rfl(((int)blockIdx.y << 4) + ((wv >> 1) << 3));  // 8-tall tile
    const int px0 = rfl(min(max(tx - 4, 0), WW - 24));              // 24-col window
    const int py0 = rfl(min(max(ty - 4, 0), HH - 16));              // 16-row window
    const int txoff = tx - px0;                   // 0..8
    const int tyoff = ty - py0;                   // 0..8

    const size_t plane = (size_t)blockIdx.z * (size_t)(HH * WW);
    const float* sp = sparse + plane;
    const float* dp = depth  + plane;

    // ---- stage 16x24 window: 3 float2 per lane per input ----
    const int r  = lane >> 2;                     // 0..15 window row
    const int c0 = (lane & 3) << 1;               // float2 col 0,2,4,6 (+8 per j)
    const float* wbs = sp + (py0 + r) * WW + px0 + c0;
    const float* wbd = dp + (py0 + r) * WW + px0 + c0;
    const f2 s20 = *(const f2*)(wbs);
    const f2 s21 = *(const f2*)(wbs + 8);
    const f2 s22 = *(const f2*)(wbs + 16);
    const f2 d20 = *(const f2*)(wbd);
    const f2 d21 = *(const f2*)(wbd + 8);
    const f2 d22 = *(const f2*)(wbd + 16);

    // ---- per-lane pixel pair (gx, gx+8) ----
    const int my = lane >> 3, mx = lane & 7;
    const int gy = ty + my, gx = tx + mx;
    const float myd0 = dp[gy * WW + gx];
    const float myd1 = dp[gy * WW + gx + 8];
    f2 nmyd; nmyd.x = -myd0; nmyd.y = -myd1;
    const int clane_w = my * TS + mx;             // per-lane table float offset

    f2 numA = splat(0.0f), denA = splat(0.0f);
    f2 numB = splat(0.0f), denB = splat(0.0f);
    const f2 crp = splat(CR);

    // SALU base: TS*(dy+15) + (dx0+23) - 8 decomposition (lane part = clane_w)
    const int sbase0 = TS * (15 - tyoff) + (23 - txoff) - 8;

    #pragma unroll
    for (int j = 0; j < 3; ++j) {
        const f2 s2 = (j == 0) ? s20 : (j == 1) ? s21 : s22;
        const f2 d2 = (j == 0) ? d20 : (j == 1) ? d21 : d22;
        #pragma unroll
        for (int k = 0; k < 2; ++k) {
            const float svk = k ? s2.y : s2.x;
            const float dvk = k ? d2.y : d2.x;
            const int sbase = sbase0 + 8 * j + k;          // SALU
            unsigned long long m = __ballot(svk != 1.0f);
            while (m) {                                     // uniform scalar loop
                const int b0 = (int)__builtin_ctzll(m);
                m &= (m - 1ull);
                {
                    const float sv_e = rlanef(svk, b0);
                    const float dv_e = rlanef(dvk, b0);
                    const int SW = sbase + (b0 >> 2) * TS + ((b0 & 3) << 1); // SALU
                    const float* tb = Tab + (SW - clane_w); // one v_sub
                    f2 tp; tp.x = tb[8]; tp.y = tb[0];      // ds_read2_b32
                    const f2 diff = nmyd + splat(dv_e);
                    const f2 q = diff * crp;
                    const f2 arg = q * diff + tp;           // pk_fma
                    f2 w; w.x = __builtin_amdgcn_exp2f(arg.x);
                    w.y = __builtin_amdgcn_exp2f(arg.y);
                    denA += w;
                    numA += w * splat(sv_e);                // pk_fma
                }
                if (m) {                                    // independent B chain
                    const int b1 = (int)__builtin_ctzll(m);
                    m &= (m - 1ull);
                    const float sv_e = rlanef(svk, b1);
                    const float dv_e = rlanef(dvk, b1);
                    const int SW = sbase + (b1 >> 2) * TS + ((b1 & 3) << 1);
                    const float* tb = Tab + (SW - clane_w);
                    f2 tp; tp.x = tb[8]; tp.y = tb[0];
                    const f2 diff = nmyd + splat(dv_e);
                    const f2 q = diff * crp;
                    const f2 arg = q * diff + tp;
                    f2 w; w.x = __builtin_amdgcn_exp2f(arg.x);
                    w.y = __builtin_amdgcn_exp2f(arg.y);
                    denB += w;
                    numB += w * splat(sv_e);
                }
            }
        }
    }

    const float n0 = numA.x + numB.x, n1 = numA.y + numB.y;
    const float e0 = denA.x + denB.x, e1 = denA.y + denB.y;
    float r0 = n0 * __builtin_amdgcn_rcpf(e0 + 1e-8f);
    r0 = (e0 < 1e-8f) ? 1.0f : r0;
    float r1 = n1 * __builtin_amdgcn_rcpf(e1 + 1e-8f);
    r1 = (e1 < 1e-8f) ? 1.0f : r1;
    float* op = out + plane + (size_t)gy * WW + gx;
    op[0] = r0;
    op[8] = r1;
}

extern "C" void kernel_launch(void* const* d_in, const int* in_sizes, int n_in,
                              void* d_out, int out_size, void* d_ws, size_t ws_size,
                              hipStream_t stream)
{
    const float* sparse = (const float*)d_in[0];
    const float* depth  = (const float*)d_in[1];
    float* out = (float*)d_out;
    dim3 grid(WW / 32, HH / 16, BB);   // 32 x 48 x 16 blocks, 4 waves each
    jbf_kernel<<<grid, dim3(256, 1, 1), 0, stream>>>(sparse, depth, out);
}